// Round 1
// baseline (628.715 us; speedup 1.0000x reference)
//
#include <hip/hip_runtime.h>
#include <hip/hip_bf16.h>

// Problem constants (derived at runtime from in_sizes for safety)
// N = 100000 nodes, E = 1600000 edges, F = 512 in-feats, C = 64 classes

#define F_IN 512
#define NCLS 64

// ---------------- degree kernels ----------------
__global__ void deg_init(float* __restrict__ deg, int n) {
    int i = blockIdx.x * blockDim.x + threadIdx.x;
    if (i < n) deg[i] = 1.0f;  // self-loop contributes 1
}

__global__ void deg_count(const int* __restrict__ dst, float* __restrict__ deg, int e) {
    int i = blockIdx.x * blockDim.x + threadIdx.x;
    if (i < e) atomicAdd(&deg[dst[i]], 1.0f);
}

__global__ void deg_rsqrt(float* __restrict__ deg, int n) {
    int i = blockIdx.x * blockDim.x + threadIdx.x;
    if (i < n) deg[i] = rsqrtf(deg[i]);  // deg >= 1 always
}

// ---------------- GEMM: h = x @ W  ([N,512] @ [512,64]) ----------------
// Block = 256 threads = 4 waves. Block handles 16 rows; each wave 4 rows.
// x rows staged in LDS; lane = output column; W loads coalesced (L2-hot).
__global__ __launch_bounds__(256) void gemm_xw(const float* __restrict__ x,
                                               const float* __restrict__ W,
                                               float* __restrict__ h, int n) {
    __shared__ __align__(16) float xs[16][F_IN];
    const int wave = threadIdx.x >> 6;
    const int lane = threadIdx.x & 63;
    const int rowBase = blockIdx.x * 16;

    // cooperative stage: 16 rows * 512 floats = 2048 float4, 256 threads -> 8 each
    const float4* xg = reinterpret_cast<const float4*>(x + (size_t)rowBase * F_IN);
    float4* xs4 = reinterpret_cast<float4*>(&xs[0][0]);
#pragma unroll
    for (int j = 0; j < 8; ++j) {
        xs4[threadIdx.x + 256 * j] = xg[threadIdx.x + 256 * j];
    }
    __syncthreads();

    const float* xr0 = &xs[wave * 4 + 0][0];
    const float* xr1 = &xs[wave * 4 + 1][0];
    const float* xr2 = &xs[wave * 4 + 2][0];
    const float* xr3 = &xs[wave * 4 + 3][0];

    float acc0 = 0.f, acc1 = 0.f, acc2 = 0.f, acc3 = 0.f;
#pragma unroll 4
    for (int k = 0; k < F_IN; k += 4) {
        float4 a0 = *reinterpret_cast<const float4*>(xr0 + k);
        float4 a1 = *reinterpret_cast<const float4*>(xr1 + k);
        float4 a2 = *reinterpret_cast<const float4*>(xr2 + k);
        float4 a3 = *reinterpret_cast<const float4*>(xr3 + k);
        float w0 = W[(k + 0) * NCLS + lane];
        float w1 = W[(k + 1) * NCLS + lane];
        float w2 = W[(k + 2) * NCLS + lane];
        float w3 = W[(k + 3) * NCLS + lane];
        acc0 += a0.x * w0 + a0.y * w1 + a0.z * w2 + a0.w * w3;
        acc1 += a1.x * w0 + a1.y * w1 + a1.z * w2 + a1.w * w3;
        acc2 += a2.x * w0 + a2.y * w1 + a2.z * w2 + a2.w * w3;
        acc3 += a3.x * w0 + a3.y * w1 + a3.z * w2 + a3.w * w3;
    }
    const int r = rowBase + wave * 4;
    h[(size_t)(r + 0) * NCLS + lane] = acc0;
    h[(size_t)(r + 1) * NCLS + lane] = acc1;
    h[(size_t)(r + 2) * NCLS + lane] = acc2;
    h[(size_t)(r + 3) * NCLS + lane] = acc3;
}

// ---------------- out init: bias + self-loop contribution ----------------
__global__ void out_init(const float* __restrict__ h, const float* __restrict__ dinv,
                         const float* __restrict__ b, float* __restrict__ out, int n) {
    int i = blockIdx.x * blockDim.x + threadIdx.x;
    if (i < n * NCLS) {
        int node = i >> 6;
        int c = i & 63;
        float d = dinv[node];
        out[i] = b[c] + h[i] * d * d;
    }
}

// ---------------- edge aggregation (atomic scatter-add) ----------------
__global__ __launch_bounds__(256) void edge_aggregate(const float* __restrict__ h,
                                                      const float* __restrict__ dinv,
                                                      const int* __restrict__ src,
                                                      const int* __restrict__ dst,
                                                      float* __restrict__ out, int e) {
    int edge = blockIdx.x * 4 + (threadIdx.x >> 6);
    int c = threadIdx.x & 63;
    if (edge < e) {
        int s = src[edge];
        int d = dst[edge];
        float norm = dinv[s] * dinv[d];
        float v = h[(size_t)s * NCLS + c] * norm;
        atomicAdd(&out[(size_t)d * NCLS + c], v);
    }
}

// ---------------- row-wise log_softmax (in place) ----------------
__global__ __launch_bounds__(256) void logsoftmax(float* __restrict__ out, int n) {
    int node = blockIdx.x * 4 + (threadIdx.x >> 6);
    int c = threadIdx.x & 63;
    if (node < n) {
        size_t idx = (size_t)node * NCLS + c;
        float v = out[idx];
        float m = v;
#pragma unroll
        for (int off = 32; off; off >>= 1) m = fmaxf(m, __shfl_xor(m, off));
        float ex = __expf(v - m);
        float s = ex;
#pragma unroll
        for (int off = 32; off; off >>= 1) s += __shfl_xor(s, off);
        out[idx] = v - m - __logf(s);
    }
}

extern "C" void kernel_launch(void* const* d_in, const int* in_sizes, int n_in,
                              void* d_out, int out_size, void* d_ws, size_t ws_size,
                              hipStream_t stream) {
    const float* x = (const float*)d_in[0];       // [N, 512]
    const float* W = (const float*)d_in[1];       // [512, 64]
    const float* b = (const float*)d_in[2];       // [64]
    const int* edge_index = (const int*)d_in[3];  // [2, E]

    const int N = in_sizes[0] / F_IN;
    const int E = in_sizes[3] / 2;
    const int* src = edge_index;
    const int* dst = edge_index + E;

    float* out = (float*)d_out;                    // [N, 64]
    float* h = (float*)d_ws;                       // [N, 64]
    float* dinv = (float*)d_ws + (size_t)N * NCLS; // [N]

    // degree: init to 1 (self loop), count dst, rsqrt
    deg_init<<<(N + 255) / 256, 256, 0, stream>>>(dinv, N);
    deg_count<<<(E + 255) / 256, 256, 0, stream>>>(dst, dinv, E);
    deg_rsqrt<<<(N + 255) / 256, 256, 0, stream>>>(dinv, N);

    // projection h = x @ W   (N = 100000 = 16 * 6250)
    gemm_xw<<<(N + 15) / 16, 256, 0, stream>>>(x, W, h, N);

    // out = b + self-loop term
    out_init<<<((size_t)N * NCLS + 255) / 256, 256, 0, stream>>>(h, dinv, b, out, N);

    // scatter-add edge messages
    edge_aggregate<<<(E + 3) / 4, 256, 0, stream>>>(h, dinv, src, dst, out, E);

    // log softmax rows in place
    logsoftmax<<<(N + 3) / 4, 256, 0, stream>>>(out, N);
}

// Round 2
// 465.032 us; speedup vs baseline: 1.3520x; 1.3520x over previous
//
#include <hip/hip_runtime.h>
#include <hip/hip_bf16.h>

#define F_IN 512
#define NCLS 64
#define SCAN_BLK 512

// ---------------- init: zero cnt + cursor ----------------
__global__ void init_zero(int* __restrict__ cnt, int* __restrict__ cursor, int n) {
    int i = blockIdx.x * blockDim.x + threadIdx.x;
    if (i < n) { cnt[i] = 0; cursor[i] = 0; }
}

// ---------------- count in-degree per dst ----------------
__global__ void deg_count(const int* __restrict__ dst, int* __restrict__ cnt, int e) {
    int i = blockIdx.x * blockDim.x + threadIdx.x;
    if (i < e) atomicAdd(&cnt[dst[i]], 1);
}

// ---------------- dinv = rsqrt(1 + cnt) ----------------
__global__ void deg_rsqrt(const int* __restrict__ cnt, float* __restrict__ dinv, int n) {
    int i = blockIdx.x * blockDim.x + threadIdx.x;
    if (i < n) dinv[i] = rsqrtf(1.0f + (float)cnt[i]);
}

// ---------------- exclusive scan (3 kernels) ----------------
__global__ __launch_bounds__(SCAN_BLK) void scan1(const int* __restrict__ cnt,
                                                  int* __restrict__ off,
                                                  int* __restrict__ partials, int n) {
    __shared__ int s[SCAN_BLK];
    int tid = threadIdx.x;
    int i = blockIdx.x * SCAN_BLK + tid;
    int v = (i < n) ? cnt[i] : 0;
    s[tid] = v;
    __syncthreads();
#pragma unroll
    for (int d = 1; d < SCAN_BLK; d <<= 1) {
        int t = (tid >= d) ? s[tid - d] : 0;
        __syncthreads();
        s[tid] += t;
        __syncthreads();
    }
    if (i < n) off[i] = s[tid] - v;  // exclusive
    if (tid == SCAN_BLK - 1) partials[blockIdx.x] = s[tid];
}

__global__ __launch_bounds__(256) void scan2(int* __restrict__ partials, int p) {
    __shared__ int s[256];
    int tid = threadIdx.x;
    int v = (tid < p) ? partials[tid] : 0;
    s[tid] = v;
    __syncthreads();
#pragma unroll
    for (int d = 1; d < 256; d <<= 1) {
        int t = (tid >= d) ? s[tid - d] : 0;
        __syncthreads();
        s[tid] += t;
        __syncthreads();
    }
    if (tid < p) partials[tid] = s[tid] - v;  // exclusive
}

__global__ void scan3(int* __restrict__ off, const int* __restrict__ partials, int n) {
    int i = blockIdx.x * blockDim.x + threadIdx.x;
    if (i < n) off[i] += partials[i / SCAN_BLK];
}

// ---------------- fill CSR edge list ----------------
__global__ void fill_csr(const int* __restrict__ src, const int* __restrict__ dst,
                         const int* __restrict__ off, int* __restrict__ cursor,
                         int* __restrict__ eidx, int e) {
    int i = blockIdx.x * blockDim.x + threadIdx.x;
    if (i < e) {
        int d = dst[i];
        int p = atomicAdd(&cursor[d], 1);
        eidx[off[d] + p] = src[i];
    }
}

// ---------------- GEMM: g = (x @ W) * dinv[row]  ([N,512]@[512,64]) ----------------
__global__ __launch_bounds__(256) void gemm_xw(const float* __restrict__ x,
                                               const float* __restrict__ W,
                                               const float* __restrict__ dinv,
                                               float* __restrict__ g, int n) {
    __shared__ __align__(16) float xs[16][F_IN];
    const int wave = threadIdx.x >> 6;
    const int lane = threadIdx.x & 63;
    const int rowBase = blockIdx.x * 16;

    const float4* xg = reinterpret_cast<const float4*>(x + (size_t)rowBase * F_IN);
    float4* xs4 = reinterpret_cast<float4*>(&xs[0][0]);
#pragma unroll
    for (int j = 0; j < 8; ++j) {
        xs4[threadIdx.x + 256 * j] = xg[threadIdx.x + 256 * j];
    }
    __syncthreads();

    const float* xr0 = &xs[wave * 4 + 0][0];
    const float* xr1 = &xs[wave * 4 + 1][0];
    const float* xr2 = &xs[wave * 4 + 2][0];
    const float* xr3 = &xs[wave * 4 + 3][0];

    float acc0 = 0.f, acc1 = 0.f, acc2 = 0.f, acc3 = 0.f;
#pragma unroll 4
    for (int k = 0; k < F_IN; k += 4) {
        float4 a0 = *reinterpret_cast<const float4*>(xr0 + k);
        float4 a1 = *reinterpret_cast<const float4*>(xr1 + k);
        float4 a2 = *reinterpret_cast<const float4*>(xr2 + k);
        float4 a3 = *reinterpret_cast<const float4*>(xr3 + k);
        float w0 = W[(k + 0) * NCLS + lane];
        float w1 = W[(k + 1) * NCLS + lane];
        float w2 = W[(k + 2) * NCLS + lane];
        float w3 = W[(k + 3) * NCLS + lane];
        acc0 += a0.x * w0 + a0.y * w1 + a0.z * w2 + a0.w * w3;
        acc1 += a1.x * w0 + a1.y * w1 + a1.z * w2 + a1.w * w3;
        acc2 += a2.x * w0 + a2.y * w1 + a2.z * w2 + a2.w * w3;
        acc3 += a3.x * w0 + a3.y * w1 + a3.z * w2 + a3.w * w3;
    }
    const int r = rowBase + wave * 4;
    g[(size_t)(r + 0) * NCLS + lane] = acc0 * dinv[r + 0];
    g[(size_t)(r + 1) * NCLS + lane] = acc1 * dinv[r + 1];
    g[(size_t)(r + 2) * NCLS + lane] = acc2 * dinv[r + 2];
    g[(size_t)(r + 3) * NCLS + lane] = acc3 * dinv[r + 3];
}

// ---------------- fused gather + bias + log_softmax ----------------
// wave per node, lane = class. acc = g[node] + sum_{in-edges} g[src];
// out = logsoftmax(acc * dinv[node] + b)
__global__ __launch_bounds__(256) void aggregate(const float* __restrict__ g,
                                                 const float* __restrict__ dinv,
                                                 const float* __restrict__ b,
                                                 const int* __restrict__ off,
                                                 const int* __restrict__ eidx,
                                                 float* __restrict__ out, int n, int e) {
    int node = blockIdx.x * 4 + (threadIdx.x >> 6);
    int c = threadIdx.x & 63;
    if (node >= n) return;

    int s0 = off[node];
    int s1 = (node + 1 < n) ? off[node + 1] : e;

    float acc = g[(size_t)node * NCLS + c];
    for (int t = s0; t < s1; ++t) {
        int s = eidx[t];
        acc += g[(size_t)s * NCLS + c];
    }
    float v = acc * dinv[node] + b[c];

    float m = v;
#pragma unroll
    for (int o = 32; o; o >>= 1) m = fmaxf(m, __shfl_xor(m, o));
    float ex = __expf(v - m);
    float sum = ex;
#pragma unroll
    for (int o = 32; o; o >>= 1) sum += __shfl_xor(sum, o);
    out[(size_t)node * NCLS + c] = v - m - __logf(sum);
}

extern "C" void kernel_launch(void* const* d_in, const int* in_sizes, int n_in,
                              void* d_out, int out_size, void* d_ws, size_t ws_size,
                              hipStream_t stream) {
    const float* x = (const float*)d_in[0];       // [N, 512]
    const float* W = (const float*)d_in[1];       // [512, 64]
    const float* b = (const float*)d_in[2];       // [64]
    const int* edge_index = (const int*)d_in[3];  // [2, E]

    const int N = in_sizes[0] / F_IN;
    const int E = in_sizes[3] / 2;
    const int* src = edge_index;
    const int* dst = edge_index + E;

    float* out = (float*)d_out;  // [N, 64]

    // workspace layout
    char* ws = (char*)d_ws;
    float* g      = (float*)ws;                 ws += (size_t)N * NCLS * 4;  // 25.6 MB
    float* dinv   = (float*)ws;                 ws += (size_t)N * 4;
    int*   cnt    = (int*)ws;                   ws += (size_t)N * 4;
    int*   cursor = (int*)ws;                   ws += (size_t)N * 4;
    int*   off    = (int*)ws;                   ws += (size_t)(N + 1) * 4;
    int*   parts  = (int*)ws;                   ws += 1024 * 4;
    int*   eidx   = (int*)ws;                   // E ints

    const int nScanBlocks = (N + SCAN_BLK - 1) / SCAN_BLK;  // 196 for N=100000

    init_zero<<<(N + 255) / 256, 256, 0, stream>>>(cnt, cursor, N);
    deg_count<<<(E + 255) / 256, 256, 0, stream>>>(dst, cnt, E);
    deg_rsqrt<<<(N + 255) / 256, 256, 0, stream>>>(cnt, dinv, N);

    scan1<<<nScanBlocks, SCAN_BLK, 0, stream>>>(cnt, off, parts, N);
    scan2<<<1, 256, 0, stream>>>(parts, nScanBlocks);
    scan3<<<(N + 255) / 256, 256, 0, stream>>>(off, parts, N);

    fill_csr<<<(E + 255) / 256, 256, 0, stream>>>(src, dst, off, cursor, eidx, E);

    gemm_xw<<<(N + 15) / 16, 256, 0, stream>>>(x, W, dinv, g, N);

    aggregate<<<(N + 3) / 4, 256, 0, stream>>>(g, dinv, b, off, eidx, out, N, E);
}

// Round 3
// 290.452 us; speedup vs baseline: 2.1646x; 1.6011x over previous
//
#include <hip/hip_runtime.h>
#include <hip/hip_bf16.h>

#define F_IN 512
#define NCLS 64
#define SCAN_BLK 512

typedef __attribute__((ext_vector_type(8))) short short8;
typedef __attribute__((ext_vector_type(4))) float f32x4;

static __device__ __forceinline__ short bf16_of(float f) {
    __hip_bfloat16 h = __float2bfloat16(f);
    short s;
    __builtin_memcpy(&s, &h, 2);
    return s;
}

// ---------------- init: zero cnt + cursor ----------------
__global__ void init_zero(int* __restrict__ cnt, int* __restrict__ cursor, int n) {
    int i = blockIdx.x * blockDim.x + threadIdx.x;
    if (i < n) { cnt[i] = 0; cursor[i] = 0; }
}

// ---------------- count in-degree per dst ----------------
__global__ void deg_count(const int* __restrict__ dst, int* __restrict__ cnt, int e) {
    int i = blockIdx.x * blockDim.x + threadIdx.x;
    if (i < e) atomicAdd(&cnt[dst[i]], 1);
}

// ---------------- dinv = rsqrt(1 + cnt) ----------------
__global__ void deg_rsqrt(const int* __restrict__ cnt, float* __restrict__ dinv, int n) {
    int i = blockIdx.x * blockDim.x + threadIdx.x;
    if (i < n) dinv[i] = rsqrtf(1.0f + (float)cnt[i]);
}

// ---------------- exclusive scan (3 kernels) ----------------
__global__ __launch_bounds__(SCAN_BLK) void scan1(const int* __restrict__ cnt,
                                                  int* __restrict__ off,
                                                  int* __restrict__ partials, int n) {
    __shared__ int s[SCAN_BLK];
    int tid = threadIdx.x;
    int i = blockIdx.x * SCAN_BLK + tid;
    int v = (i < n) ? cnt[i] : 0;
    s[tid] = v;
    __syncthreads();
#pragma unroll
    for (int d = 1; d < SCAN_BLK; d <<= 1) {
        int t = (tid >= d) ? s[tid - d] : 0;
        __syncthreads();
        s[tid] += t;
        __syncthreads();
    }
    if (i < n) off[i] = s[tid] - v;  // exclusive
    if (tid == SCAN_BLK - 1) partials[blockIdx.x] = s[tid];
}

__global__ __launch_bounds__(256) void scan2(int* __restrict__ partials, int p) {
    __shared__ int s[256];
    int tid = threadIdx.x;
    int v = (tid < p) ? partials[tid] : 0;
    s[tid] = v;
    __syncthreads();
#pragma unroll
    for (int d = 1; d < 256; d <<= 1) {
        int t = (tid >= d) ? s[tid - d] : 0;
        __syncthreads();
        s[tid] += t;
        __syncthreads();
    }
    if (tid < p) partials[tid] = s[tid] - v;  // exclusive
}

__global__ void scan3(int* __restrict__ off, const int* __restrict__ partials, int n) {
    int i = blockIdx.x * blockDim.x + threadIdx.x;
    if (i < n) off[i] += partials[i / SCAN_BLK];
}

// ---------------- fill CSR edge list ----------------
__global__ void fill_csr(const int* __restrict__ src, const int* __restrict__ dst,
                         const int* __restrict__ off, int* __restrict__ cursor,
                         int* __restrict__ eidx, int e) {
    int i = blockIdx.x * blockDim.x + threadIdx.x;
    if (i < e) {
        int d = dst[i];
        int p = atomicAdd(&cursor[d], 1);
        eidx[off[d] + p] = src[i];
    }
}

// ---------------- W -> bf16 B-fragment layout ----------------
// Wb[((c*16 + kk)*64 + lane)*8 + j] = bf16(W[(kk*32 + (lane>>4)*8 + j)*64 + c*16 + (lane&15)])
// so a wave's B-frag for (col-tile c, k-tile kk) is one coalesced 16B/lane load.
__global__ void wconvert(const float* __restrict__ W, short* __restrict__ Wb) {
    int t = blockIdx.x * blockDim.x + threadIdx.x;  // 4096 threads
    if (t >= 4096) return;
    int c = t >> 10;
    int kk = (t >> 6) & 15;
    int l = t & 63;
    short8 v;
#pragma unroll
    for (int j = 0; j < 8; ++j) {
        v[j] = bf16_of(W[(size_t)(kk * 32 + (l >> 4) * 8 + j) * NCLS + c * 16 + (l & 15)]);
    }
    reinterpret_cast<short8*>(Wb)[t] = v;
}

// ---------------- MFMA GEMM: g = (x @ W) * dinv[row] ----------------
// Block = 256 thr = 4 waves, 64 rows/block, 16 rows/wave, full 64 cols.
// A-frag (16x32): lane l holds x[row = base + (l&15)][k = kk*32 + (l>>4)*8 + j], j=0..7
// B-frag from pre-shuffled Wb. C/D: col = l&15, row = (l>>4)*4 + reg (m89-verified).
__global__ __launch_bounds__(256) void gemm_mfma(const float* __restrict__ x,
                                                 const short* __restrict__ Wb,
                                                 const float* __restrict__ dinv,
                                                 float* __restrict__ g, int n) {
    const int wave = threadIdx.x >> 6;
    const int lane = threadIdx.x & 63;
    const int rowTile = blockIdx.x * 64 + wave * 16;

    int arow = rowTile + (lane & 15);
    if (arow > n - 1) arow = n - 1;  // tail clamp (stores are guarded)
    const float* xr = x + (size_t)arow * F_IN + ((lane >> 4) * 8);

    const short8* wb8 = reinterpret_cast<const short8*>(Wb);

    f32x4 acc0 = {0.f, 0.f, 0.f, 0.f};
    f32x4 acc1 = {0.f, 0.f, 0.f, 0.f};
    f32x4 acc2 = {0.f, 0.f, 0.f, 0.f};
    f32x4 acc3 = {0.f, 0.f, 0.f, 0.f};

#pragma unroll 4
    for (int kk = 0; kk < 16; ++kk) {
        float4 f0 = *reinterpret_cast<const float4*>(xr + kk * 32);
        float4 f1 = *reinterpret_cast<const float4*>(xr + kk * 32 + 4);
        short8 a;
        a[0] = bf16_of(f0.x); a[1] = bf16_of(f0.y);
        a[2] = bf16_of(f0.z); a[3] = bf16_of(f0.w);
        a[4] = bf16_of(f1.x); a[5] = bf16_of(f1.y);
        a[6] = bf16_of(f1.z); a[7] = bf16_of(f1.w);
        short8 b0 = wb8[(0 * 16 + kk) * 64 + lane];
        short8 b1 = wb8[(1 * 16 + kk) * 64 + lane];
        short8 b2 = wb8[(2 * 16 + kk) * 64 + lane];
        short8 b3 = wb8[(3 * 16 + kk) * 64 + lane];
        acc0 = __builtin_amdgcn_mfma_f32_16x16x32_bf16(a, b0, acc0, 0, 0, 0);
        acc1 = __builtin_amdgcn_mfma_f32_16x16x32_bf16(a, b1, acc1, 0, 0, 0);
        acc2 = __builtin_amdgcn_mfma_f32_16x16x32_bf16(a, b2, acc2, 0, 0, 0);
        acc3 = __builtin_amdgcn_mfma_f32_16x16x32_bf16(a, b3, acc3, 0, 0, 0);
    }

    const int col = lane & 15;
    const int rbase = rowTile + (lane >> 4) * 4;
#pragma unroll
    for (int j = 0; j < 4; ++j) {
        int r = rbase + j;
        if (r < n) {
            float dv = dinv[r];
            float* go = g + (size_t)r * NCLS + col;
            go[0]  = acc0[j] * dv;
            go[16] = acc1[j] * dv;
            go[32] = acc2[j] * dv;
            go[48] = acc3[j] * dv;
        }
    }
}

// ---------------- fused gather + bias + log_softmax ----------------
// 4 nodes per wave: sub = lane>>4 selects node, (lane&15) covers 64 ch as float4.
__global__ __launch_bounds__(256) void aggregate(const float* __restrict__ g,
                                                 const float* __restrict__ dinv,
                                                 const float* __restrict__ b,
                                                 const int* __restrict__ off,
                                                 const int* __restrict__ eidx,
                                                 float* __restrict__ out, int n, int e) {
    const int wave = threadIdx.x >> 6;
    const int lane = threadIdx.x & 63;
    const int sub = lane >> 4;
    const int li = lane & 15;
    const int node = (blockIdx.x * 4 + wave) * 4 + sub;
    if (node >= n) return;

    const int s0 = off[node];
    const int s1 = (node + 1 < n) ? off[node + 1] : e;

    const float4* g4 = reinterpret_cast<const float4*>(g);
    float4 acc = g4[(size_t)node * 16 + li];

    int t = s0;
    for (; t + 2 <= s1; t += 2) {
        int sa = eidx[t];
        int sb = eidx[t + 1];
        float4 va = g4[(size_t)sa * 16 + li];
        float4 vb = g4[(size_t)sb * 16 + li];
        acc.x += va.x + vb.x;
        acc.y += va.y + vb.y;
        acc.z += va.z + vb.z;
        acc.w += va.w + vb.w;
    }
    if (t < s1) {
        int sa = eidx[t];
        float4 va = g4[(size_t)sa * 16 + li];
        acc.x += va.x; acc.y += va.y; acc.z += va.z; acc.w += va.w;
    }

    const float dn = dinv[node];
    const float4 bb = reinterpret_cast<const float4*>(b)[li];
    float4 v;
    v.x = acc.x * dn + bb.x;
    v.y = acc.y * dn + bb.y;
    v.z = acc.z * dn + bb.z;
    v.w = acc.w * dn + bb.w;

    float m = fmaxf(fmaxf(v.x, v.y), fmaxf(v.z, v.w));
#pragma unroll
    for (int o = 1; o < 16; o <<= 1) m = fmaxf(m, __shfl_xor(m, o));
    float ex = __expf(v.x - m) + __expf(v.y - m) + __expf(v.z - m) + __expf(v.w - m);
#pragma unroll
    for (int o = 1; o < 16; o <<= 1) ex += __shfl_xor(ex, o);
    const float lg = m + __logf(ex);

    float4 r;
    r.x = v.x - lg; r.y = v.y - lg; r.z = v.z - lg; r.w = v.w - lg;
    reinterpret_cast<float4*>(out)[(size_t)node * 16 + li] = r;
}

extern "C" void kernel_launch(void* const* d_in, const int* in_sizes, int n_in,
                              void* d_out, int out_size, void* d_ws, size_t ws_size,
                              hipStream_t stream) {
    const float* x = (const float*)d_in[0];       // [N, 512]
    const float* W = (const float*)d_in[1];       // [512, 64]
    const float* b = (const float*)d_in[2];       // [64]
    const int* edge_index = (const int*)d_in[3];  // [2, E]

    const int N = in_sizes[0] / F_IN;
    const int E = in_sizes[3] / 2;
    const int* src = edge_index;
    const int* dst = edge_index + E;

    float* out = (float*)d_out;  // [N, 64]

    // workspace layout (16B-aligned pieces first)
    char* ws = (char*)d_ws;
    float* g      = (float*)ws;  ws += (size_t)N * NCLS * 4;   // 25.6 MB
    short* Wb     = (short*)ws;  ws += 4096 * 16;              // 64 KB, bf16 B-frag layout
    float* dinv   = (float*)ws;  ws += (size_t)N * 4;
    int*   cnt    = (int*)ws;    ws += (size_t)N * 4;
    int*   cursor = (int*)ws;    ws += (size_t)N * 4;
    int*   off    = (int*)ws;    ws += (size_t)(N + 4) * 4;
    int*   parts  = (int*)ws;    ws += 1024 * 4;
    int*   eidx   = (int*)ws;    // E ints

    const int nScanBlocks = (N + SCAN_BLK - 1) / SCAN_BLK;

    init_zero<<<(N + 255) / 256, 256, 0, stream>>>(cnt, cursor, N);
    deg_count<<<(E + 255) / 256, 256, 0, stream>>>(dst, cnt, E);
    deg_rsqrt<<<(N + 255) / 256, 256, 0, stream>>>(cnt, dinv, N);

    scan1<<<nScanBlocks, SCAN_BLK, 0, stream>>>(cnt, off, parts, N);
    scan2<<<1, 256, 0, stream>>>(parts, nScanBlocks);
    scan3<<<(N + 255) / 256, 256, 0, stream>>>(off, parts, N);

    fill_csr<<<(E + 255) / 256, 256, 0, stream>>>(src, dst, off, cursor, eidx, E);

    wconvert<<<16, 256, 0, stream>>>(W, Wb);

    gemm_mfma<<<(N + 63) / 64, 256, 0, stream>>>(x, Wb, dinv, g, N);

    aggregate<<<(N + 15) / 16, 256, 0, stream>>>(g, dinv, b, off, eidx, out, N, E);
}

// Round 4
// 255.104 us; speedup vs baseline: 2.4645x; 1.1386x over previous
//
#include <hip/hip_runtime.h>
#include <hip/hip_bf16.h>

#define F_IN 512
#define NCLS 64
#define SCAN_BLK 512

typedef __attribute__((ext_vector_type(8))) short short8;
typedef __attribute__((ext_vector_type(4))) float f32x4;

static __device__ __forceinline__ short bf16_of(float f) {
    __hip_bfloat16 h = __float2bfloat16(f);
    short s;
    __builtin_memcpy(&s, &h, 2);
    return s;
}
static __device__ __forceinline__ float b2f(short s) {
    unsigned u = ((unsigned)(unsigned short)s) << 16;
    float f;
    __builtin_memcpy(&f, &u, 4);
    return f;
}

// ---------------- count in-degree per dst ----------------
__global__ void deg_count(const int* __restrict__ dst, int* __restrict__ cnt, int e) {
    int i = blockIdx.x * blockDim.x + threadIdx.x;
    if (i < e) atomicAdd(&cnt[dst[i]], 1);
}

// ---------------- exclusive scan (3 kernels); scan1 also emits dinv ----------------
__global__ __launch_bounds__(SCAN_BLK) void scan1(const int* __restrict__ cnt,
                                                  int* __restrict__ off,
                                                  int* __restrict__ partials,
                                                  float* __restrict__ dinv, int n) {
    __shared__ int s[SCAN_BLK];
    int tid = threadIdx.x;
    int i = blockIdx.x * SCAN_BLK + tid;
    int v = (i < n) ? cnt[i] : 0;
    if (i < n) dinv[i] = rsqrtf(1.0f + (float)v);
    s[tid] = v;
    __syncthreads();
#pragma unroll
    for (int d = 1; d < SCAN_BLK; d <<= 1) {
        int t = (tid >= d) ? s[tid - d] : 0;
        __syncthreads();
        s[tid] += t;
        __syncthreads();
    }
    if (i < n) off[i] = s[tid] - v;  // exclusive
    if (tid == SCAN_BLK - 1) partials[blockIdx.x] = s[tid];
}

__global__ __launch_bounds__(256) void scan2(int* __restrict__ partials, int p) {
    __shared__ int s[256];
    int tid = threadIdx.x;
    int v = (tid < p) ? partials[tid] : 0;
    s[tid] = v;
    __syncthreads();
#pragma unroll
    for (int d = 1; d < 256; d <<= 1) {
        int t = (tid >= d) ? s[tid - d] : 0;
        __syncthreads();
        s[tid] += t;
        __syncthreads();
    }
    if (tid < p) partials[tid] = s[tid] - v;  // exclusive
}

__global__ void scan3(int* __restrict__ off, const int* __restrict__ partials, int n) {
    int i = blockIdx.x * blockDim.x + threadIdx.x;
    if (i < n) off[i] += partials[i / SCAN_BLK];
}

// ---------------- fill CSR edge list ----------------
__global__ void fill_csr(const int* __restrict__ src, const int* __restrict__ dst,
                         const int* __restrict__ off, int* __restrict__ cursor,
                         int* __restrict__ eidx, int e) {
    int i = blockIdx.x * blockDim.x + threadIdx.x;
    if (i < e) {
        int d = dst[i];
        int p = atomicAdd(&cursor[d], 1);
        eidx[off[d] + p] = src[i];
    }
}

// ---------------- W -> bf16 B-fragment layout ----------------
__global__ void wconvert(const float* __restrict__ W, short* __restrict__ Wb) {
    int t = blockIdx.x * blockDim.x + threadIdx.x;  // 4096 threads
    if (t >= 4096) return;
    int c = t >> 10;
    int kk = (t >> 6) & 15;
    int l = t & 63;
    short8 v;
#pragma unroll
    for (int j = 0; j < 8; ++j) {
        v[j] = bf16_of(W[(size_t)(kk * 32 + (l >> 4) * 8 + j) * NCLS + c * 16 + (l & 15)]);
    }
    reinterpret_cast<short8*>(Wb)[t] = v;
}

// ---------------- MFMA GEMM: g = bf16((x @ W) * dinv[row]) ----------------
__global__ __launch_bounds__(256) void gemm_mfma(const float* __restrict__ x,
                                                 const short* __restrict__ Wb,
                                                 const float* __restrict__ dinv,
                                                 short* __restrict__ g, int n) {
    const int wave = threadIdx.x >> 6;
    const int lane = threadIdx.x & 63;
    const int rowTile = blockIdx.x * 64 + wave * 16;

    int arow = rowTile + (lane & 15);
    if (arow > n - 1) arow = n - 1;  // tail clamp (stores are guarded)
    const float* xr = x + (size_t)arow * F_IN + ((lane >> 4) * 8);

    const short8* wb8 = reinterpret_cast<const short8*>(Wb);

    f32x4 acc0 = {0.f, 0.f, 0.f, 0.f};
    f32x4 acc1 = {0.f, 0.f, 0.f, 0.f};
    f32x4 acc2 = {0.f, 0.f, 0.f, 0.f};
    f32x4 acc3 = {0.f, 0.f, 0.f, 0.f};

#pragma unroll 4
    for (int kk = 0; kk < 16; ++kk) {
        float4 f0 = *reinterpret_cast<const float4*>(xr + kk * 32);
        float4 f1 = *reinterpret_cast<const float4*>(xr + kk * 32 + 4);
        short8 a;
        a[0] = bf16_of(f0.x); a[1] = bf16_of(f0.y);
        a[2] = bf16_of(f0.z); a[3] = bf16_of(f0.w);
        a[4] = bf16_of(f1.x); a[5] = bf16_of(f1.y);
        a[6] = bf16_of(f1.z); a[7] = bf16_of(f1.w);
        short8 b0 = wb8[(0 * 16 + kk) * 64 + lane];
        short8 b1 = wb8[(1 * 16 + kk) * 64 + lane];
        short8 b2 = wb8[(2 * 16 + kk) * 64 + lane];
        short8 b3 = wb8[(3 * 16 + kk) * 64 + lane];
        acc0 = __builtin_amdgcn_mfma_f32_16x16x32_bf16(a, b0, acc0, 0, 0, 0);
        acc1 = __builtin_amdgcn_mfma_f32_16x16x32_bf16(a, b1, acc1, 0, 0, 0);
        acc2 = __builtin_amdgcn_mfma_f32_16x16x32_bf16(a, b2, acc2, 0, 0, 0);
        acc3 = __builtin_amdgcn_mfma_f32_16x16x32_bf16(a, b3, acc3, 0, 0, 0);
    }

    const int col = lane & 15;
    const int rbase = rowTile + (lane >> 4) * 4;
#pragma unroll
    for (int j = 0; j < 4; ++j) {
        int r = rbase + j;
        if (r < n) {
            float dv = dinv[r];
            short* go = g + (size_t)r * NCLS + col;
            go[0]  = bf16_of(acc0[j] * dv);
            go[16] = bf16_of(acc1[j] * dv);
            go[32] = bf16_of(acc2[j] * dv);
            go[48] = bf16_of(acc3[j] * dv);
        }
    }
}

// ---------------- fused gather + bias + log_softmax ----------------
// 8 nodes per wave: 8-lane sub-group per node; lane handles 8 channels (short8 = 16B).
__global__ __launch_bounds__(256) void aggregate(const short* __restrict__ g,
                                                 const float* __restrict__ dinv,
                                                 const float* __restrict__ b,
                                                 const int* __restrict__ off,
                                                 const int* __restrict__ eidx,
                                                 float* __restrict__ out, int n, int e) {
    const int wave = threadIdx.x >> 6;
    const int lane = threadIdx.x & 63;
    const int grp = lane >> 3;   // node sub-group 0..7
    const int li = lane & 7;     // covers channels li*8 .. li*8+7
    const int node = (blockIdx.x * 4 + wave) * 8 + grp;
    if (node >= n) return;

    const int s0 = off[node];
    const int s1 = (node + 1 < n) ? off[node + 1] : e;

    const short8* g8 = reinterpret_cast<const short8*>(g);  // 8 short8 per row

    float acc[8];
    {
        short8 v = g8[(size_t)node * 8 + li];
#pragma unroll
        for (int c = 0; c < 8; ++c) acc[c] = b2f(v[c]);
    }

    int t = s0;
    for (; t + 4 <= s1; t += 4) {
        int sa = eidx[t];
        int sb = eidx[t + 1];
        int sc = eidx[t + 2];
        int sd = eidx[t + 3];
        short8 va = g8[(size_t)sa * 8 + li];
        short8 vb = g8[(size_t)sb * 8 + li];
        short8 vc = g8[(size_t)sc * 8 + li];
        short8 vd = g8[(size_t)sd * 8 + li];
#pragma unroll
        for (int c = 0; c < 8; ++c)
            acc[c] += (b2f(va[c]) + b2f(vb[c])) + (b2f(vc[c]) + b2f(vd[c]));
    }
    for (; t < s1; ++t) {
        int sa = eidx[t];
        short8 va = g8[(size_t)sa * 8 + li];
#pragma unroll
        for (int c = 0; c < 8; ++c) acc[c] += b2f(va[c]);
    }

    const float dn = dinv[node];
    const float4 b0 = reinterpret_cast<const float4*>(b)[li * 2];
    const float4 b1 = reinterpret_cast<const float4*>(b)[li * 2 + 1];
    float v[8];
    v[0] = acc[0] * dn + b0.x; v[1] = acc[1] * dn + b0.y;
    v[2] = acc[2] * dn + b0.z; v[3] = acc[3] * dn + b0.w;
    v[4] = acc[4] * dn + b1.x; v[5] = acc[5] * dn + b1.y;
    v[6] = acc[6] * dn + b1.z; v[7] = acc[7] * dn + b1.w;

    float m = v[0];
#pragma unroll
    for (int c = 1; c < 8; ++c) m = fmaxf(m, v[c]);
#pragma unroll
    for (int o = 1; o < 8; o <<= 1) m = fmaxf(m, __shfl_xor(m, o));

    float ex = 0.f;
#pragma unroll
    for (int c = 0; c < 8; ++c) ex += __expf(v[c] - m);
#pragma unroll
    for (int o = 1; o < 8; o <<= 1) ex += __shfl_xor(ex, o);
    const float lg = m + __logf(ex);

    float4 r0, r1;
    r0.x = v[0] - lg; r0.y = v[1] - lg; r0.z = v[2] - lg; r0.w = v[3] - lg;
    r1.x = v[4] - lg; r1.y = v[5] - lg; r1.z = v[6] - lg; r1.w = v[7] - lg;
    float4* o4 = reinterpret_cast<float4*>(out + (size_t)node * NCLS);
    o4[li * 2] = r0;
    o4[li * 2 + 1] = r1;
}

extern "C" void kernel_launch(void* const* d_in, const int* in_sizes, int n_in,
                              void* d_out, int out_size, void* d_ws, size_t ws_size,
                              hipStream_t stream) {
    const float* x = (const float*)d_in[0];       // [N, 512]
    const float* W = (const float*)d_in[1];       // [512, 64]
    const float* b = (const float*)d_in[2];       // [64]
    const int* edge_index = (const int*)d_in[3];  // [2, E]

    const int N = in_sizes[0] / F_IN;
    const int E = in_sizes[3] / 2;
    const int* src = edge_index;
    const int* dst = edge_index + E;

    float* out = (float*)d_out;  // [N, 64]

    // workspace layout (16B-aligned pieces first)
    char* ws = (char*)d_ws;
    short* g      = (short*)ws;  ws += (size_t)N * NCLS * 2;   // 12.8 MB bf16
    short* Wb     = (short*)ws;  ws += 4096 * 16;              // 64 KB
    float* dinv   = (float*)ws;  ws += (size_t)N * 4;
    int*   cnt    = (int*)ws;    ws += (size_t)N * 4;
    int*   cursor = (int*)ws;    ws += (size_t)N * 4;          // contiguous with cnt
    int*   off    = (int*)ws;    ws += (size_t)(N + 4) * 4;
    int*   parts  = (int*)ws;    ws += 1024 * 4;
    int*   eidx   = (int*)ws;    // E ints

    const int nScanBlocks = (N + SCAN_BLK - 1) / SCAN_BLK;

    hipMemsetAsync(cnt, 0, (size_t)2 * N * 4, stream);  // cnt + cursor

    deg_count<<<(E + 255) / 256, 256, 0, stream>>>(dst, cnt, E);

    scan1<<<nScanBlocks, SCAN_BLK, 0, stream>>>(cnt, off, parts, dinv, N);
    scan2<<<1, 256, 0, stream>>>(parts, nScanBlocks);
    scan3<<<(N + 255) / 256, 256, 0, stream>>>(off, parts, N);

    fill_csr<<<(E + 255) / 256, 256, 0, stream>>>(src, dst, off, cursor, eidx, E);

    wconvert<<<16, 256, 0, stream>>>(W, Wb);

    gemm_mfma<<<(N + 63) / 64, 256, 0, stream>>>(x, Wb, dinv, g, N);

    aggregate<<<(N + 31) / 32, 256, 0, stream>>>(g, dinv, b, off, eidx, out, N, E);
}